// Round 2
// baseline (374.863 us; speedup 1.0000x reference)
//
#include <hip/hip_runtime.h>
#include <math.h>

#define NN 8192

typedef __attribute__((ext_vector_type(8))) short short8;
typedef __attribute__((ext_vector_type(4))) short short4v;
typedef __attribute__((ext_vector_type(4))) float f32x4;
typedef __attribute__((ext_vector_type(4))) int int4v;

__device__ __forceinline__ short f2bf(float f) {
    union { float f; unsigned u; } v; v.f = f;
    unsigned r = v.u + 0x7fffu + ((v.u >> 16) & 1u);
    return (short)(r >> 16);
}

__device__ __forceinline__ f32x4 zero4() {
    f32x4 v; v[0] = 0.f; v[1] = 0.f; v[2] = 0.f; v[3] = 0.f; return v;
}

// ---------- K0: WT[f][k] = bf16(W[k][f]) ----------
__global__ void k0_wt(const float* __restrict__ W, short* __restrict__ WT) {
    int idx = blockIdx.x * 256 + threadIdx.x;
    if (idx < 256 * 128) {
        int k = idx & 255;
        int f = idx >> 8;
        WT[f * 256 + k] = f2bf(W[k * 128 + f]);
    }
}

// ---------- K1: h = x@W (bf16 MFMA); s1,s2 fp32; hT bf16 [128][8192] ----------
__global__ __launch_bounds__(128) void k1_h(
        const float* __restrict__ x, const short* __restrict__ WT,
        const float* __restrict__ a, short* __restrict__ hT,
        float* __restrict__ s1, float* __restrict__ s2) {
    const int w = threadIdx.x >> 6;
    const int l = threadIdx.x & 63;
    const int quad = l >> 4;
    const int fr = l & 15;
    const int i0 = blockIdx.x * 32 + w * 16;

    f32x4 acc[8];
#pragma unroll
    for (int t = 0; t < 8; ++t) acc[t] = zero4();

    const float* xrow = x + (size_t)(i0 + fr) * 256;
#pragma unroll
    for (int kk = 0; kk < 8; ++kk) {
        const int k0 = kk * 32 + quad * 8;
        f32x4 xa = *(const f32x4*)(xrow + k0);
        f32x4 xb = *(const f32x4*)(xrow + k0 + 4);
        short8 av;
#pragma unroll
        for (int e = 0; e < 4; ++e) { av[e] = f2bf(xa[e]); av[4 + e] = f2bf(xb[e]); }
#pragma unroll
        for (int t = 0; t < 8; ++t) {
            short8 bv = *(const short8*)(WT + (t * 16 + fr) * 256 + k0);
            acc[t] = __builtin_amdgcn_mfma_f32_16x16x32_bf16(av, bv, acc[t], 0, 0, 0);
        }
    }

    float s1p[4] = {0.f, 0.f, 0.f, 0.f};
    float s2p[4] = {0.f, 0.f, 0.f, 0.f};
#pragma unroll
    for (int t = 0; t < 8; ++t) {
        float a1v = a[t * 16 + fr];
        float a2v = a[128 + t * 16 + fr];
#pragma unroll
        for (int r = 0; r < 4; ++r) {
            s1p[r] += acc[t][r] * a1v;
            s2p[r] += acc[t][r] * a2v;
        }
    }
#pragma unroll
    for (int r = 0; r < 4; ++r) {
#pragma unroll
        for (int m = 1; m < 16; m <<= 1) {
            s1p[r] += __shfl_xor(s1p[r], m, 64);
            s2p[r] += __shfl_xor(s2p[r], m, 64);
        }
    }
    if (fr == 0) {
#pragma unroll
        for (int r = 0; r < 4; ++r) {
            s1[i0 + quad * 4 + r] = s1p[r];
            s2[i0 + quad * 4 + r] = s2p[r];
        }
    }

#pragma unroll
    for (int t = 0; t < 8; ++t) {
        short4v hv;
#pragma unroll
        for (int r = 0; r < 4; ++r) hv[r] = f2bf(acc[t][r]);
        *(short4v*)(hT + (size_t)(t * 16 + fr) * NN + i0 + quad * 4) = hv;
    }
}

// ---------- K2: fused masked softmax + PV, pipelined, row/j wave split ----------
// waves: rh = w>>2 picks row half (16 rows), wj = w&3 picks j strip.
template<int JSPLIT, bool PARTIAL>
__global__ __launch_bounds__(512, 8) void k2_attn(
        const int* __restrict__ adj, const short* __restrict__ hT,
        const float* __restrict__ s1g, const float* __restrict__ s2g,
        float* __restrict__ pvp, float* __restrict__ zp,
        float* __restrict__ out) {
    constexpr int JW = NN / JSPLIT;       // j width per block
    constexpr int NIT = JW / 128;         // iterations per wave (4 strips x 32)
    __shared__ float red[8192];           // 4 regions x 2048 floats
    __shared__ float zbuf[128];

    const int w = threadIdx.x >> 6;
    const int l = threadIdx.x & 63;
    const int quad = l >> 4;
    const int fr = l & 15;
    const int rh = w >> 2;                // row half 0/1
    const int wj = w & 3;                 // j strip 0..3
    const int rb = blockIdx.x / JSPLIT;
    const int jb = blockIdx.x % JSPLIT;
    const int i0 = rb * 32;
    const int r16 = i0 + rh * 16;         // this wave's 16 rows base
    const int jbase = jb * JW + wj * 32 + quad * 8;

    const float LOG2E = 1.44269504088896f;
    const float s1v = s1g[r16 + fr] * LOG2E;

    f32x4 acc[8];
#pragma unroll
    for (int t = 0; t < 8; ++t) acc[t] = zero4();
    float zacc = 0.f;

    const size_t row0 = (size_t)(r16 + fr) * NN;

    auto jof = [&](int it) { int c = it < NIT ? it : NIT - 1; return jbase + c * 128; };

    short8 bvA[8], bvB[8];
    f32x4 s2Aa, s2Ab, s2Ba, s2Bb;
    int4v gA0, gA1, gB0, gB1;
    short8 paA, paB;

#define LOAD_BV(B, it) { const int j_ = jof(it); \
    _Pragma("unroll") for (int t = 0; t < 8; ++t) \
        B[t] = *(const short8*)(hT + (size_t)(t * 16 + fr) * NN + j_); }

#define LOAD_S2(Sa, Sb, it) { const int j_ = jof(it); \
    f32x4 ta_ = *(const f32x4*)(s2g + j_); \
    f32x4 tb_ = *(const f32x4*)(s2g + j_ + 4); \
    _Pragma("unroll") for (int e = 0; e < 4; ++e) { Sa[e] = ta_[e] * LOG2E; Sb[e] = tb_[e] * LOG2E; } }

#define LOAD_ADJ(G0, G1, it) { const int j_ = jof(it); \
    G0 = *(const int4v*)(adj + row0 + j_); \
    G1 = *(const int4v*)(adj + row0 + j_ + 4); }

#define MAKEP(PA, G0, G1, Sa, Sb) { float zs_ = 0.f; \
    _Pragma("unroll") for (int e = 0; e < 8; ++e) { \
        const float s2e_ = (e < 4) ? Sa[e & 3] : Sb[e & 3]; \
        const int gv_ = (e < 4) ? G0[e & 3] : G1[e & 3]; \
        float s_ = s1v + s2e_; \
        float t_ = fmaxf(s_, 0.2f * s_); \
        float p_ = (gv_ > 0) ? exp2f(t_) : 0.f; \
        zs_ += p_; PA[e] = f2bf(p_); } \
    zacc += zs_; }

#define DOMFMA(PA, BV) { \
    _Pragma("unroll") for (int t = 0; t < 8; ++t) \
        acc[t] = __builtin_amdgcn_mfma_f32_16x16x32_bf16(PA, BV[t], acc[t], 0, 0, 0); }

    // prologue: adj+s2 two tiles deep, bv one deep
    LOAD_ADJ(gA0, gA1, 0);
    LOAD_ADJ(gB0, gB1, 1);
    LOAD_S2(s2Aa, s2Ab, 0);
    LOAD_S2(s2Ba, s2Bb, 1);
    LOAD_BV(bvA, 0);

    for (int it = 0; it < NIT; it += 2) {
        MAKEP(paA, gA0, gA1, s2Aa, s2Ab);       // waits s2A (2 phases old), gA in regs
        LOAD_ADJ(gA0, gA1, it + 2);             // depth-2 prefetch
        LOAD_S2(s2Aa, s2Ab, it + 2);
        LOAD_BV(bvB, it + 1);                   // depth-1 prefetch
        DOMFMA(paA, bvA);                       // waits bvA (1 phase old)

        MAKEP(paB, gB0, gB1, s2Ba, s2Bb);
        LOAD_ADJ(gB0, gB1, it + 3);
        LOAD_S2(s2Ba, s2Bb, it + 3);
        LOAD_BV(bvA, it + 2);
        DOMFMA(paB, bvB);
    }

    // Z: reduce across quads (lanes with same fr share a row)
    zacc += __shfl_xor(zacc, 16, 64);
    zacc += __shfl_xor(zacc, 32, 64);
    if (l < 16) zbuf[w * 16 + l] = zacc;

    auto rwrite = [&](float* base) {
#pragma unroll
        for (int t = 0; t < 8; ++t) *(f32x4*)(base + (t * 64 + l) * 4) = acc[t];
    };
    auto radd = [&](const float* base) {
#pragma unroll
        for (int t = 0; t < 8; ++t) acc[t] += *(const f32x4*)(base + (t * 64 + l) * 4);
    };

    // per-half tree over 4 partials; halves in parallel. regions: R[2h], R[2h+1]
    float* R0 = red + rh * 4096;
    float* R1 = red + rh * 4096 + 2048;
    if (wj == 1) rwrite(R0);
    if (wj == 3) rwrite(R1);
    __syncthreads();
    if (wj == 0) radd(R0);
    if (wj == 2) radd(R1);
    __syncthreads();
    if (wj == 2) rwrite(R0);
    __syncthreads();

    if (wj == 0) {
        radd(R0);   // acc = sum of this half's 4 partials
#pragma unroll
        for (int r = 0; r < 4; ++r) {
            const int irow = quad * 4 + r;
            float z = zbuf[(rh * 4 + 0) * 16 + irow] + zbuf[(rh * 4 + 1) * 16 + irow]
                    + zbuf[(rh * 4 + 2) * 16 + irow] + zbuf[(rh * 4 + 3) * 16 + irow];
            const int grow = r16 + irow;
            if (PARTIAL) {
                if (fr == 0) zp[(size_t)jb * NN + grow] = z;
                float* orow = pvp + ((size_t)jb * NN + grow) * 128;
#pragma unroll
                for (int t = 0; t < 8; ++t) orow[t * 16 + fr] = acc[t][r];
            } else {
                const float inv = 1.0f / z;
                float* orow = out + (size_t)grow * 128;
#pragma unroll
                for (int t = 0; t < 8; ++t) {
                    float v = acc[t][r] * inv;
                    orow[t * 16 + fr] = (v > 0.f) ? v : expm1f(v);
                }
            }
        }
    }
#undef LOAD_BV
#undef LOAD_S2
#undef LOAD_ADJ
#undef MAKEP
#undef DOMFMA
}

// ---------- K3: sum partials, divide by Z, ELU ----------
__global__ __launch_bounds__(256) void k3_fin(
        const float* __restrict__ pvp, const float* __restrict__ zp,
        float* __restrict__ out, int jsplit) {
    const int idx = blockIdx.x * 256 + threadIdx.x;   // 8192*32 f32x4 chunks
    const int row = idx >> 5;
    const int c = (idx & 31) << 2;
    f32x4 s = zero4();
    float z = 0.f;
    for (int p = 0; p < jsplit; ++p) {
        s += *(const f32x4*)(pvp + ((size_t)p * NN + row) * 128 + c);
        z += zp[(size_t)p * NN + row];
    }
    const float inv = 1.0f / z;
    f32x4 o;
#pragma unroll
    for (int e = 0; e < 4; ++e) {
        float v = s[e] * inv;
        o[e] = (v > 0.f) ? v : expm1f(v);
    }
    *(f32x4*)(out + (size_t)row * 128 + c) = o;
}

extern "C" void kernel_launch(void* const* d_in, const int* in_sizes, int n_in,
                              void* d_out, int out_size, void* d_ws, size_t ws_size,
                              hipStream_t stream) {
    const float* x   = (const float*)d_in[0];   // 8192 x 256
    const float* W   = (const float*)d_in[1];   // 256 x 128
    const float* a   = (const float*)d_in[2];   // 256
    const int*   adj = (const int*)d_in[3];     // 8192 x 8192
    float* out = (float*)d_out;                 // 8192 x 128

    char* ws = (char*)d_ws;
    short* hT = (short*)ws;                                     // 2 MB
    float* s1 = (float*)(ws + (size_t)2 * 1024 * 1024);         // 32 KB
    float* s2 = (float*)(ws + (size_t)2 * 1024 * 1024 + 32768); // 32 KB
    short* WT = (short*)(ws + (size_t)2 * 1024 * 1024 + 65536); // 64 KB
    const size_t base = (size_t)2 * 1024 * 1024 + 131072;

    auto need = [&](size_t js) {
        return base + js * ((size_t)NN * 128 * 4) + js * ((size_t)NN * 4);
    };
    int jsplit;
    if (ws_size >= need(4)) jsplit = 4;
    else if (ws_size >= need(2)) jsplit = 2;
    else if (ws_size >= need(1)) jsplit = 1;
    else jsplit = 0;   // fallback: direct-output k2

    float* pvp = (float*)(ws + base);
    float* zp  = (float*)(ws + base + (size_t)(jsplit > 0 ? jsplit : 1) * NN * 128 * 4);

    k0_wt<<<128, 256, 0, stream>>>(W, WT);
    k1_h<<<256, 128, 0, stream>>>(x, WT, a, hT, s1, s2);

    if (jsplit == 4) {
        k2_attn<4, true><<<1024, 512, 0, stream>>>(adj, hT, s1, s2, pvp, zp, nullptr);
        k3_fin<<<1024, 256, 0, stream>>>(pvp, zp, out, 4);
    } else if (jsplit == 2) {
        k2_attn<2, true><<<512, 512, 0, stream>>>(adj, hT, s1, s2, pvp, zp, nullptr);
        k3_fin<<<1024, 256, 0, stream>>>(pvp, zp, out, 2);
    } else if (jsplit == 1) {
        k2_attn<1, true><<<256, 512, 0, stream>>>(adj, hT, s1, s2, pvp, zp, nullptr);
        k3_fin<<<1024, 256, 0, stream>>>(pvp, zp, out, 1);
    } else {
        k2_attn<1, false><<<256, 512, 0, stream>>>(adj, hT, s1, s2, nullptr, nullptr, out);
    }
}

// Round 3
// 196.041 us; speedup vs baseline: 1.9122x; 1.9122x over previous
//
#include <hip/hip_runtime.h>
#include <math.h>

#define NN 8192

typedef __attribute__((ext_vector_type(8))) short short8;
typedef __attribute__((ext_vector_type(4))) short short4v;
typedef __attribute__((ext_vector_type(4))) float f32x4;
typedef __attribute__((ext_vector_type(4))) int int4v;

__device__ __forceinline__ short f2bf(float f) {
    union { float f; unsigned u; } v; v.f = f;
    unsigned r = v.u + 0x7fffu + ((v.u >> 16) & 1u);
    return (short)(r >> 16);
}

__device__ __forceinline__ f32x4 zero4() {
    f32x4 v; v[0] = 0.f; v[1] = 0.f; v[2] = 0.f; v[3] = 0.f; return v;
}

// ---------- K0: WT[f][k] = bf16(W[k][f]) ----------
__global__ void k0_wt(const float* __restrict__ W, short* __restrict__ WT) {
    int idx = blockIdx.x * 256 + threadIdx.x;
    if (idx < 256 * 128) {
        int k = idx & 255;
        int f = idx >> 8;
        WT[f * 256 + k] = f2bf(W[k * 128 + f]);
    }
}

// ---------- K1: h = x@W (bf16 MFMA); s1,s2 fp32; hT bf16 [128][8192] ----------
__global__ __launch_bounds__(128) void k1_h(
        const float* __restrict__ x, const short* __restrict__ WT,
        const float* __restrict__ a, short* __restrict__ hT,
        float* __restrict__ s1, float* __restrict__ s2) {
    const int w = threadIdx.x >> 6;
    const int l = threadIdx.x & 63;
    const int quad = l >> 4;
    const int fr = l & 15;
    const int i0 = blockIdx.x * 32 + w * 16;

    f32x4 acc[8];
#pragma unroll
    for (int t = 0; t < 8; ++t) acc[t] = zero4();

    const float* xrow = x + (size_t)(i0 + fr) * 256;
#pragma unroll
    for (int kk = 0; kk < 8; ++kk) {
        const int k0 = kk * 32 + quad * 8;
        f32x4 xa = *(const f32x4*)(xrow + k0);
        f32x4 xb = *(const f32x4*)(xrow + k0 + 4);
        short8 av;
#pragma unroll
        for (int e = 0; e < 4; ++e) { av[e] = f2bf(xa[e]); av[4 + e] = f2bf(xb[e]); }
#pragma unroll
        for (int t = 0; t < 8; ++t) {
            short8 bv = *(const short8*)(WT + (t * 16 + fr) * 256 + k0);
            acc[t] = __builtin_amdgcn_mfma_f32_16x16x32_bf16(av, bv, acc[t], 0, 0, 0);
        }
    }

    float s1p[4] = {0.f, 0.f, 0.f, 0.f};
    float s2p[4] = {0.f, 0.f, 0.f, 0.f};
#pragma unroll
    for (int t = 0; t < 8; ++t) {
        float a1v = a[t * 16 + fr];
        float a2v = a[128 + t * 16 + fr];
#pragma unroll
        for (int r = 0; r < 4; ++r) {
            s1p[r] += acc[t][r] * a1v;
            s2p[r] += acc[t][r] * a2v;
        }
    }
#pragma unroll
    for (int r = 0; r < 4; ++r) {
#pragma unroll
        for (int m = 1; m < 16; m <<= 1) {
            s1p[r] += __shfl_xor(s1p[r], m, 64);
            s2p[r] += __shfl_xor(s2p[r], m, 64);
        }
    }
    if (fr == 0) {
#pragma unroll
        for (int r = 0; r < 4; ++r) {
            s1[i0 + quad * 4 + r] = s1p[r];
            s2[i0 + quad * 4 + r] = s2p[r];
        }
    }

#pragma unroll
    for (int t = 0; t < 8; ++t) {
        short4v hv;
#pragma unroll
        for (int r = 0; r < 4; ++r) hv[r] = f2bf(acc[t][r]);
        *(short4v*)(hT + (size_t)(t * 16 + fr) * NN + i0 + quad * 4) = hv;
    }
}

// ---------- K2: fused masked softmax + PV ----------
// waves: rh = w>>2 row half (16 rows), wj = w&3 j strip.
// VGPR budget: acc32 + bv32 + adj(cur8+nxt8) + s2(cur8+nxt8) + pa4 + addr ~= 115
// -> __launch_bounds__(512,4): cap 128 VGPR, 4 waves/SIMD, NO SPILL (R2 lesson:
//    (512,8) forces <=64 VGPR -> 460MB scratch traffic).
template<int JSPLIT, bool PARTIAL>
__global__ __launch_bounds__(512, 4) void k2_attn(
        const int* __restrict__ adj, const short* __restrict__ hT,
        const float* __restrict__ s1g, const float* __restrict__ s2g,
        float* __restrict__ pvp, float* __restrict__ zp,
        float* __restrict__ out) {
    constexpr int JW = NN / JSPLIT;
    constexpr int NIT = JW / 128;
    __shared__ float red[8192];
    __shared__ float zbuf[128];

    const int w = threadIdx.x >> 6;
    const int l = threadIdx.x & 63;
    const int quad = l >> 4;
    const int fr = l & 15;
    const int rh = w >> 2;
    const int wj = w & 3;
    const int rb = blockIdx.x / JSPLIT;
    const int jb = blockIdx.x % JSPLIT;
    const int i0 = rb * 32;
    const int r16 = i0 + rh * 16;
    const int jbase = jb * JW + wj * 32 + quad * 8;

    const float LOG2E = 1.44269504088896f;
    const float s1v = s1g[r16 + fr] * LOG2E;   // premultiplied; lrelu commutes (L2E>0)

    f32x4 acc[8];
#pragma unroll
    for (int t = 0; t < 8; ++t) acc[t] = zero4();
    float zacc = 0.f;

    const size_t row0 = (size_t)(r16 + fr) * NN;

    auto jof = [&](int it) { int c = it < NIT ? it : NIT - 1; return jbase + c * 128; };

    short8 bv[8];
    f32x4 s2a, s2b, s2na, s2nb;
    int4v g0, g1, n0, n1;
    short8 pa;

#define LOAD_BV(it) { const int j_ = jof(it); \
    _Pragma("unroll") for (int t = 0; t < 8; ++t) \
        bv[t] = *(const short8*)(hT + (size_t)(t * 16 + fr) * NN + j_); }

#define LOAD_S2(Sa, Sb, it) { const int j_ = jof(it); \
    Sa = *(const f32x4*)(s2g + j_); \
    Sb = *(const f32x4*)(s2g + j_ + 4); }

#define LOAD_ADJ(G0, G1, it) { const int j_ = jof(it); \
    G0 = *(const int4v*)(adj + row0 + j_); \
    G1 = *(const int4v*)(adj + row0 + j_ + 4); }

#define MAKEP() { float zs_ = 0.f; \
    _Pragma("unroll") for (int e = 0; e < 8; ++e) { \
        const float s2e_ = (e < 4) ? s2a[e & 3] : s2b[e & 3]; \
        const int gv_ = (e < 4) ? g0[e & 3] : g1[e & 3]; \
        float s_ = fmaf(s2e_, LOG2E, s1v); \
        float t_ = fmaxf(s_, 0.2f * s_); \
        float p_ = (gv_ > 0) ? exp2f(t_) : 0.f; \
        zs_ += p_; pa[e] = f2bf(p_); } \
    zacc += zs_; }

    // prologue: adj + s2 for iteration 0 (depth-1 steady state below)
    LOAD_ADJ(g0, g1, 0);
    LOAD_S2(s2a, s2b, 0);

    for (int it = 0; it < NIT; ++it) {
        // bv FIRST, then next-iter adj/s2: the MFMA's vmcnt wait for bv
        // (older in FIFO) leaves the adj/s2 prefetch outstanding across
        // the whole next MAKEP+MFMA phase.
        LOAD_BV(it);
        LOAD_ADJ(n0, n1, it + 1);
        LOAD_S2(s2na, s2nb, it + 1);

        MAKEP();                         // pure VALU on prev-iter regs; overlaps bv flight

#pragma unroll
        for (int t = 0; t < 8; ++t)
            acc[t] = __builtin_amdgcn_mfma_f32_16x16x32_bf16(pa, bv[t], acc[t], 0, 0, 0);

        g0 = n0; g1 = n1; s2a = s2na; s2b = s2nb;
    }

    // Z: reduce across quads (lanes with same fr share a row)
    zacc += __shfl_xor(zacc, 16, 64);
    zacc += __shfl_xor(zacc, 32, 64);
    if (l < 16) zbuf[w * 16 + l] = zacc;

    auto rwrite = [&](float* base) {
#pragma unroll
        for (int t = 0; t < 8; ++t) *(f32x4*)(base + (t * 64 + l) * 4) = acc[t];
    };
    auto radd = [&](const float* base) {
#pragma unroll
        for (int t = 0; t < 8; ++t) acc[t] += *(const f32x4*)(base + (t * 64 + l) * 4);
    };

    float* R0 = red + rh * 4096;
    float* R1 = red + rh * 4096 + 2048;
    if (wj == 1) rwrite(R0);
    if (wj == 3) rwrite(R1);
    __syncthreads();
    if (wj == 0) radd(R0);
    if (wj == 2) radd(R1);
    __syncthreads();
    if (wj == 2) rwrite(R0);
    __syncthreads();

    if (wj == 0) {
        radd(R0);   // acc = sum of this half's 4 partials
#pragma unroll
        for (int r = 0; r < 4; ++r) {
            const int irow = quad * 4 + r;
            float z = zbuf[(rh * 4 + 0) * 16 + irow] + zbuf[(rh * 4 + 1) * 16 + irow]
                    + zbuf[(rh * 4 + 2) * 16 + irow] + zbuf[(rh * 4 + 3) * 16 + irow];
            const int grow = r16 + irow;
            if (PARTIAL) {
                if (fr == 0) zp[(size_t)jb * NN + grow] = z;
                float* orow = pvp + ((size_t)jb * NN + grow) * 128;
#pragma unroll
                for (int t = 0; t < 8; ++t) orow[t * 16 + fr] = acc[t][r];
            } else {
                const float inv = 1.0f / z;
                float* orow = out + (size_t)grow * 128;
#pragma unroll
                for (int t = 0; t < 8; ++t) {
                    float v = acc[t][r] * inv;
                    orow[t * 16 + fr] = (v > 0.f) ? v : expm1f(v);
                }
            }
        }
    }
#undef LOAD_BV
#undef LOAD_S2
#undef LOAD_ADJ
#undef MAKEP
}

// ---------- K3: sum partials, divide by Z, ELU ----------
__global__ __launch_bounds__(256) void k3_fin(
        const float* __restrict__ pvp, const float* __restrict__ zp,
        float* __restrict__ out, int jsplit) {
    const int idx = blockIdx.x * 256 + threadIdx.x;
    const int row = idx >> 5;
    const int c = (idx & 31) << 2;
    f32x4 s = zero4();
    float z = 0.f;
    for (int p = 0; p < jsplit; ++p) {
        s += *(const f32x4*)(pvp + ((size_t)p * NN + row) * 128 + c);
        z += zp[(size_t)p * NN + row];
    }
    const float inv = 1.0f / z;
    f32x4 o;
#pragma unroll
    for (int e = 0; e < 4; ++e) {
        float v = s[e] * inv;
        o[e] = (v > 0.f) ? v : expm1f(v);
    }
    *(f32x4*)(out + (size_t)row * 128 + c) = o;
}

extern "C" void kernel_launch(void* const* d_in, const int* in_sizes, int n_in,
                              void* d_out, int out_size, void* d_ws, size_t ws_size,
                              hipStream_t stream) {
    const float* x   = (const float*)d_in[0];   // 8192 x 256
    const float* W   = (const float*)d_in[1];   // 256 x 128
    const float* a   = (const float*)d_in[2];   // 256
    const int*   adj = (const int*)d_in[3];     // 8192 x 8192
    float* out = (float*)d_out;                 // 8192 x 128

    char* ws = (char*)d_ws;
    short* hT = (short*)ws;                                     // 2 MB
    float* s1 = (float*)(ws + (size_t)2 * 1024 * 1024);         // 32 KB
    float* s2 = (float*)(ws + (size_t)2 * 1024 * 1024 + 32768); // 32 KB
    short* WT = (short*)(ws + (size_t)2 * 1024 * 1024 + 65536); // 64 KB
    const size_t base = (size_t)2 * 1024 * 1024 + 131072;

    auto need = [&](size_t js) {
        return base + js * ((size_t)NN * 128 * 4) + js * ((size_t)NN * 4);
    };
    int jsplit;
    if (ws_size >= need(4)) jsplit = 4;
    else if (ws_size >= need(2)) jsplit = 2;
    else if (ws_size >= need(1)) jsplit = 1;
    else jsplit = 0;

    float* pvp = (float*)(ws + base);
    float* zp  = (float*)(ws + base + (size_t)(jsplit > 0 ? jsplit : 1) * NN * 128 * 4);

    k0_wt<<<128, 256, 0, stream>>>(W, WT);
    k1_h<<<256, 128, 0, stream>>>(x, WT, a, hT, s1, s2);

    if (jsplit == 4) {
        k2_attn<4, true><<<1024, 512, 0, stream>>>(adj, hT, s1, s2, pvp, zp, nullptr);
        k3_fin<<<1024, 256, 0, stream>>>(pvp, zp, out, 4);
    } else if (jsplit == 2) {
        k2_attn<2, true><<<512, 512, 0, stream>>>(adj, hT, s1, s2, pvp, zp, nullptr);
        k3_fin<<<1024, 256, 0, stream>>>(pvp, zp, out, 2);
    } else if (jsplit == 1) {
        k2_attn<1, true><<<256, 512, 0, stream>>>(adj, hT, s1, s2, pvp, zp, nullptr);
        k3_fin<<<1024, 256, 0, stream>>>(pvp, zp, out, 1);
    } else {
        k2_attn<1, false><<<256, 512, 0, stream>>>(adj, hT, s1, s2, nullptr, nullptr, out);
    }
}

// Round 4
// 191.969 us; speedup vs baseline: 1.9527x; 1.0212x over previous
//
#include <hip/hip_runtime.h>
#include <math.h>

#define NN 8192

typedef __attribute__((ext_vector_type(8))) short short8;
typedef __attribute__((ext_vector_type(4))) short short4v;
typedef __attribute__((ext_vector_type(4))) float f32x4;
typedef __attribute__((ext_vector_type(4))) int int4v;

#define L2E 1.4426950408889634f

__device__ __forceinline__ short f2bf(float f) {
    union { float f; unsigned u; } v; v.f = f;
    unsigned r = v.u + 0x7fffu + ((v.u >> 16) & 1u);
    return (short)(r >> 16);
}

__device__ __forceinline__ f32x4 zero4() {
    f32x4 v; v[0] = 0.f; v[1] = 0.f; v[2] = 0.f; v[3] = 0.f; return v;
}

// ---------- K0: WT[f][k] = bf16(W[k][f]) ----------
__global__ void k0_wt(const float* __restrict__ W, short* __restrict__ WT) {
    int idx = blockIdx.x * 256 + threadIdx.x;
    if (idx < 256 * 128) {
        int k = idx & 255;
        int f = idx >> 8;
        WT[f * 256 + k] = f2bf(W[k * 128 + f]);
    }
}

// ---------- K1: h = x@W (bf16 MFMA); E1p/E1n/E2p/E2n; hT bf16 [128][8192] ----------
__global__ __launch_bounds__(128) void k1_h(
        const float* __restrict__ x, const short* __restrict__ WT,
        const float* __restrict__ a, short* __restrict__ hT,
        float* __restrict__ E1p, float* __restrict__ E1n,
        float* __restrict__ E2p, float* __restrict__ E2n) {
    const int w = threadIdx.x >> 6;
    const int l = threadIdx.x & 63;
    const int quad = l >> 4;
    const int fr = l & 15;
    const int i0 = blockIdx.x * 32 + w * 16;

    f32x4 acc[8];
#pragma unroll
    for (int t = 0; t < 8; ++t) acc[t] = zero4();

    const float* xrow = x + (size_t)(i0 + fr) * 256;
#pragma unroll
    for (int kk = 0; kk < 8; ++kk) {
        const int k0 = kk * 32 + quad * 8;
        f32x4 xa = *(const f32x4*)(xrow + k0);
        f32x4 xb = *(const f32x4*)(xrow + k0 + 4);
        short8 av;
#pragma unroll
        for (int e = 0; e < 4; ++e) { av[e] = f2bf(xa[e]); av[4 + e] = f2bf(xb[e]); }
#pragma unroll
        for (int t = 0; t < 8; ++t) {
            short8 bv = *(const short8*)(WT + (t * 16 + fr) * 256 + k0);
            acc[t] = __builtin_amdgcn_mfma_f32_16x16x32_bf16(av, bv, acc[t], 0, 0, 0);
        }
    }

    float s1p[4] = {0.f, 0.f, 0.f, 0.f};
    float s2p[4] = {0.f, 0.f, 0.f, 0.f};
#pragma unroll
    for (int t = 0; t < 8; ++t) {
        float a1v = a[t * 16 + fr];
        float a2v = a[128 + t * 16 + fr];
#pragma unroll
        for (int r = 0; r < 4; ++r) {
            s1p[r] += acc[t][r] * a1v;
            s2p[r] += acc[t][r] * a2v;
        }
    }
#pragma unroll
    for (int r = 0; r < 4; ++r) {
#pragma unroll
        for (int m = 1; m < 16; m <<= 1) {
            s1p[r] += __shfl_xor(s1p[r], m, 64);
            s2p[r] += __shfl_xor(s2p[r], m, 64);
        }
    }
    if (fr == 0) {
#pragma unroll
        for (int r = 0; r < 4; ++r) {
            const int i = i0 + quad * 4 + r;
            const float v1 = s1p[r];
            const float v2 = s2p[r];
            E1p[i] = exp2f(v1 * L2E);
            E1n[i] = exp2f(v1 * (0.2f * L2E));
            E2p[i] = exp2f(v2 * L2E);
            E2n[i] = exp2f(v2 * (0.2f * L2E));
        }
    }

#pragma unroll
    for (int t = 0; t < 8; ++t) {
        short4v hv;
#pragma unroll
        for (int r = 0; r < 4; ++r) hv[r] = f2bf(acc[t][r]);
        *(short4v*)(hT + (size_t)(t * 16 + fr) * NN + i0 + quad * 4) = hv;
    }
}

// ---------- K2: fused masked softmax + PV ----------
// 256 threads = 4 waves, all share 16 rows, j-split 4 ways.
// Separable P: no exp in loop. Loads per iter: C(4) -> bv(8) -> adj_next(2);
// vmcnt FIFO: MAKEP waits only C, MFMA waits only bv, adj stays in flight.
// sched_barrier(0) pins the cluster (R3 lesson: compiler sank bv loads into
// the MFMA chain -> VGPR 44 + full-latency serialization).
template<int JSPLIT, bool PARTIAL>
__global__ __launch_bounds__(256, 4) void k2_attn(
        const int* __restrict__ adj, const short* __restrict__ hT,
        const float* __restrict__ E1p, const float* __restrict__ E1n,
        const float* __restrict__ E2p, const float* __restrict__ E2n,
        float* __restrict__ pvp, float* __restrict__ zp,
        float* __restrict__ out) {
    constexpr int JW = NN / JSPLIT;
    constexpr int NIT = JW / 128;         // 4 waves x 32 j per iteration
    __shared__ float red[3 * 2048];       // 3 reduction regions (waves 1..3)
    __shared__ float zbuf[64];

    const int w = threadIdx.x >> 6;
    const int l = threadIdx.x & 63;
    const int quad = l >> 4;
    const int fr = l & 15;
    const int rb = blockIdx.x / JSPLIT;
    const int jb = blockIdx.x % JSPLIT;
    const int r16 = rb * 16;
    const int jbase = jb * JW + w * 32 + quad * 8;

    const float Rp = E1p[r16 + fr];
    const float Rn = E1n[r16 + fr];
    const float thr = 1.0f / Rp;          // Cp >= thr  <=>  s1+s2 >= 0

    f32x4 acc[8];
#pragma unroll
    for (int t = 0; t < 8; ++t) acc[t] = zero4();
    float zacc = 0.f;

    const size_t row0 = (size_t)(r16 + fr) * NN;

    int4v g0, g1, n0, n1;
    f32x4 cpa, cpb, cna, cnb;
    short8 bv[8];
    short8 pa;

    // prologue: adj for iteration 0
    {
        const int j = jbase;
        g0 = *(const int4v*)(adj + row0 + j);
        g1 = *(const int4v*)(adj + row0 + j + 4);
    }

    for (int it = 0; it < NIT; ++it) {
        const int j = jbase + it * 128;
        const int itn = (it + 1 < NIT) ? it + 1 : it;
        const int jn = jbase + itn * 128;

        // ---- load cluster: C first (oldest), bv, adj-next (youngest) ----
        cpa = *(const f32x4*)(E2p + j);
        cpb = *(const f32x4*)(E2p + j + 4);
        cna = *(const f32x4*)(E2n + j);
        cnb = *(const f32x4*)(E2n + j + 4);
#pragma unroll
        for (int t = 0; t < 8; ++t)
            bv[t] = *(const short8*)(hT + (size_t)(t * 16 + fr) * NN + j);
        n0 = *(const int4v*)(adj + row0 + jn);
        n1 = *(const int4v*)(adj + row0 + jn + 4);
        __builtin_amdgcn_sched_barrier(0);

        // ---- P from registers: adj (prefetched last iter) + C (just loaded) ----
        {
            float zs = 0.f;
#pragma unroll
            for (int e = 0; e < 8; ++e) {
                const float cp = (e < 4) ? cpa[e & 3] : cpb[e & 3];
                const float cn = (e < 4) ? cna[e & 3] : cnb[e & 3];
                const int gv = (e < 4) ? g0[e & 3] : g1[e & 3];
                const bool hi = cp >= thr;
                const float fc = hi ? cp : cn;
                const float rf = hi ? Rp : Rn;
                float p = fc * rf;
                p = (gv > 0) ? p : 0.f;
                zs += p;
                pa[e] = f2bf(p);
            }
            zacc += zs;
        }

#pragma unroll
        for (int t = 0; t < 8; ++t)
            acc[t] = __builtin_amdgcn_mfma_f32_16x16x32_bf16(pa, bv[t], acc[t], 0, 0, 0);

        g0 = n0; g1 = n1;
    }

    // Z: reduce across quads (lanes with same fr share a row)
    zacc += __shfl_xor(zacc, 16, 64);
    zacc += __shfl_xor(zacc, 32, 64);
    if (l < 16) zbuf[w * 16 + l] = zacc;

    if (w > 0) {
        float* base = red + (w - 1) * 2048;
#pragma unroll
        for (int t = 0; t < 8; ++t) *(f32x4*)(base + (t * 64 + l) * 4) = acc[t];
    }
    __syncthreads();

    if (w == 0) {
#pragma unroll
        for (int rg = 0; rg < 3; ++rg) {
            const float* base = red + rg * 2048;
#pragma unroll
            for (int t = 0; t < 8; ++t) acc[t] += *(const f32x4*)(base + (t * 64 + l) * 4);
        }
#pragma unroll
        for (int r = 0; r < 4; ++r) {
            const int irow = quad * 4 + r;
            const float z = zbuf[irow] + zbuf[16 + irow] + zbuf[32 + irow] + zbuf[48 + irow];
            const int grow = r16 + irow;
            if (PARTIAL) {
                if (fr == 0) zp[(size_t)jb * NN + grow] = z;
                float* orow = pvp + ((size_t)jb * NN + grow) * 128;
#pragma unroll
                for (int t = 0; t < 8; ++t) orow[t * 16 + fr] = acc[t][r];
            } else {
                const float inv = 1.0f / z;
                float* orow = out + (size_t)grow * 128;
#pragma unroll
                for (int t = 0; t < 8; ++t) {
                    float v = acc[t][r] * inv;
                    orow[t * 16 + fr] = (v > 0.f) ? v : expm1f(v);
                }
            }
        }
    }
}

// ---------- K3: sum partials, divide by Z, ELU ----------
__global__ __launch_bounds__(256) void k3_fin(
        const float* __restrict__ pvp, const float* __restrict__ zp,
        float* __restrict__ out, int jsplit) {
    const int idx = blockIdx.x * 256 + threadIdx.x;
    const int row = idx >> 5;
    const int c = (idx & 31) << 2;
    f32x4 s = zero4();
    float z = 0.f;
    for (int p = 0; p < jsplit; ++p) {
        s += *(const f32x4*)(pvp + ((size_t)p * NN + row) * 128 + c);
        z += zp[(size_t)p * NN + row];
    }
    const float inv = 1.0f / z;
    f32x4 o;
#pragma unroll
    for (int e = 0; e < 4; ++e) {
        float v = s[e] * inv;
        o[e] = (v > 0.f) ? v : expm1f(v);
    }
    *(f32x4*)(out + (size_t)row * 128 + c) = o;
}

extern "C" void kernel_launch(void* const* d_in, const int* in_sizes, int n_in,
                              void* d_out, int out_size, void* d_ws, size_t ws_size,
                              hipStream_t stream) {
    const float* x   = (const float*)d_in[0];   // 8192 x 256
    const float* W   = (const float*)d_in[1];   // 256 x 128
    const float* a   = (const float*)d_in[2];   // 256
    const int*   adj = (const int*)d_in[3];     // 8192 x 8192
    float* out = (float*)d_out;                 // 8192 x 128

    char* ws = (char*)d_ws;
    const size_t MB = 1024 * 1024;
    short* hT  = (short*)ws;                          // 2 MB
    float* E1p = (float*)(ws + 2 * MB);               // 32 KB each
    float* E1n = (float*)(ws + 2 * MB + 32768);
    float* E2p = (float*)(ws + 2 * MB + 65536);
    float* E2n = (float*)(ws + 2 * MB + 98304);
    short* WT  = (short*)(ws + 2 * MB + 131072);      // 64 KB
    const size_t base = 2 * MB + 196608;

    auto need = [&](size_t js) {
        return base + js * ((size_t)NN * 128 * 4) + js * ((size_t)NN * 4);
    };
    int jsplit;
    if (ws_size >= need(2)) jsplit = 2;
    else if (ws_size >= need(1)) jsplit = 1;
    else jsplit = 0;

    float* pvp = (float*)(ws + base);
    float* zp  = (float*)(ws + base + (size_t)(jsplit > 0 ? jsplit : 1) * NN * 128 * 4);

    k0_wt<<<128, 256, 0, stream>>>(W, WT);
    k1_h<<<256, 128, 0, stream>>>(x, WT, a, hT, E1p, E1n, E2p, E2n);

    if (jsplit == 2) {
        k2_attn<2, true><<<1024, 256, 0, stream>>>(adj, hT, E1p, E1n, E2p, E2n, pvp, zp, nullptr);
        k3_fin<<<1024, 256, 0, stream>>>(pvp, zp, out, 2);
    } else if (jsplit == 1) {
        k2_attn<1, true><<<512, 256, 0, stream>>>(adj, hT, E1p, E1n, E2p, E2n, pvp, zp, nullptr);
        k3_fin<<<1024, 256, 0, stream>>>(pvp, zp, out, 1);
    } else {
        k2_attn<1, false><<<512, 256, 0, stream>>>(adj, hT, E1p, E1n, E2p, E2n, nullptr, nullptr, out);
    }
}

// Round 5
// 97.001 us; speedup vs baseline: 3.8645x; 1.9790x over previous
//
#include <hip/hip_runtime.h>
#include <math.h>

#define NN 8192

typedef __attribute__((ext_vector_type(8))) short short8;
typedef __attribute__((ext_vector_type(4))) short short4v;
typedef __attribute__((ext_vector_type(4))) float f32x4;
typedef __attribute__((ext_vector_type(4))) int int4v;

#define L2E 1.4426950408889634f

typedef __attribute__((address_space(3))) unsigned lds_u32;
typedef __attribute__((address_space(1))) unsigned g_u32;

__device__ __forceinline__ void gll16(const void* g, void* l) {
    __builtin_amdgcn_global_load_lds((const g_u32*)g, (lds_u32*)l, 16, 0, 0);
}

__device__ __forceinline__ short f2bf(float f) {
    union { float f; unsigned u; } v; v.f = f;
    unsigned r = v.u + 0x7fffu + ((v.u >> 16) & 1u);
    return (short)(r >> 16);
}

__device__ __forceinline__ f32x4 zero4() {
    f32x4 v; v[0] = 0.f; v[1] = 0.f; v[2] = 0.f; v[3] = 0.f; return v;
}

// ---------- K0: WT[f][k] = bf16(W[k][f]) ----------
__global__ void k0_wt(const float* __restrict__ W, short* __restrict__ WT) {
    int idx = blockIdx.x * 256 + threadIdx.x;
    if (idx < 256 * 128) {
        int k = idx & 255;
        int f = idx >> 8;
        WT[f * 256 + k] = f2bf(W[k * 128 + f]);
    }
}

// ---------- K1: h = x@W (bf16 MFMA); E1p/E1n/E2p/E2n; hT bf16 [128][8192] ----------
__global__ __launch_bounds__(128) void k1_h(
        const float* __restrict__ x, const short* __restrict__ WT,
        const float* __restrict__ a, short* __restrict__ hT,
        float* __restrict__ E1p, float* __restrict__ E1n,
        float* __restrict__ E2p, float* __restrict__ E2n) {
    const int w = threadIdx.x >> 6;
    const int l = threadIdx.x & 63;
    const int quad = l >> 4;
    const int fr = l & 15;
    const int i0 = blockIdx.x * 32 + w * 16;

    f32x4 acc[8];
#pragma unroll
    for (int t = 0; t < 8; ++t) acc[t] = zero4();

    const float* xrow = x + (size_t)(i0 + fr) * 256;
#pragma unroll
    for (int kk = 0; kk < 8; ++kk) {
        const int k0 = kk * 32 + quad * 8;
        f32x4 xa = *(const f32x4*)(xrow + k0);
        f32x4 xb = *(const f32x4*)(xrow + k0 + 4);
        short8 av;
#pragma unroll
        for (int e = 0; e < 4; ++e) { av[e] = f2bf(xa[e]); av[4 + e] = f2bf(xb[e]); }
#pragma unroll
        for (int t = 0; t < 8; ++t) {
            short8 bv = *(const short8*)(WT + (t * 16 + fr) * 256 + k0);
            acc[t] = __builtin_amdgcn_mfma_f32_16x16x32_bf16(av, bv, acc[t], 0, 0, 0);
        }
    }

    float s1p[4] = {0.f, 0.f, 0.f, 0.f};
    float s2p[4] = {0.f, 0.f, 0.f, 0.f};
#pragma unroll
    for (int t = 0; t < 8; ++t) {
        float a1v = a[t * 16 + fr];
        float a2v = a[128 + t * 16 + fr];
#pragma unroll
        for (int r = 0; r < 4; ++r) {
            s1p[r] += acc[t][r] * a1v;
            s2p[r] += acc[t][r] * a2v;
        }
    }
#pragma unroll
    for (int r = 0; r < 4; ++r) {
#pragma unroll
        for (int m = 1; m < 16; m <<= 1) {
            s1p[r] += __shfl_xor(s1p[r], m, 64);
            s2p[r] += __shfl_xor(s2p[r], m, 64);
        }
    }
    if (fr == 0) {
#pragma unroll
        for (int r = 0; r < 4; ++r) {
            const int i = i0 + quad * 4 + r;
            const float v1 = s1p[r];
            const float v2 = s2p[r];
            E1p[i] = exp2f(v1 * L2E);
            E1n[i] = exp2f(v1 * (0.2f * L2E));
            E2p[i] = exp2f(v2 * L2E);
            E2n[i] = exp2f(v2 * (0.2f * L2E));
        }
    }

#pragma unroll
    for (int t = 0; t < 8; ++t) {
        short4v hv;
#pragma unroll
        for (int r = 0; r < 4; ++r) hv[r] = f2bf(acc[t][r]);
        *(short4v*)(hT + (size_t)(t * 16 + fr) * NN + i0 + quad * 4) = hv;
    }
}

// ---------- K2: 2-phase LDS-staged masked-softmax + PV ----------
// Block: 32 rows x JW cols. 4 waves = 2 row-halves (rh) x 2 j-halves (wj).
// Per step (KB=64 j): stage adj[32][64] (8KB) + hT[128][64] bf16 (16KB) via
// global_load_lds into double-buffered LDS; barrier-synced 2-phase pipeline.
// Bank conflicts on the strided LDS reads fixed by XOR swizzle
// phys = logical ^ ((row&7)<<4), applied as pre-swizzled GLOBAL source
// (linear gll dest) + same XOR on the read side (involution).
template<int JSPLIT, bool PARTIAL>
__global__ __launch_bounds__(256, 2) void k2_attn(
        const int* __restrict__ adj, const short* __restrict__ hT,
        const float* __restrict__ E1p, const float* __restrict__ E1n,
        const float* __restrict__ E2p, const float* __restrict__ E2n,
        float* __restrict__ pvp, float* __restrict__ zp,
        float* __restrict__ out) {
    constexpr int JW = NN / JSPLIT;
    constexpr int NSTEP = JW / 64;
    // LDS map: [0,32768) hT dbuf (2x16KB); [32768,49152) adj dbuf (2x8KB);
    // [49152,49408) zbuf. Reduction region aliases hT after final barrier.
    __shared__ __align__(16) char lds_c[49408];

    const int tid = threadIdx.x;
    const int w = tid >> 6;
    const int l = tid & 63;
    const int quad = l >> 4;
    const int fr = l & 15;
    const int rh = w >> 1;
    const int wj = w & 1;
    const int rb = blockIdx.x / JSPLIT;
    const int jb = blockIdx.x % JSPLIT;
    const int r32 = rb * 32;
    const int jbb = jb * JW;

    const int myrow = r32 + rh * 16 + fr;     // this lane's P row
    const float Rp = E1p[myrow];
    const float Rn = E1n[myrow];
    const float thr = 1.0f / Rp;              // Cp >= thr  <=>  s1+s2 >= 0

    // ---- precomputed per-lane pre-swizzled global sources ----
    const char* hsrc[4];
    {
        const char* hbase = (const char*)hT;
#pragma unroll
        for (int p = 0; p < 4; ++p) {
            const int o = p * 4096 + tid * 16;        // LDS-linear offset
            const int row = o >> 7;                   // feature row (128B/row)
            const int colb = o & 127;
            hsrc[p] = hbase + (size_t)row * (NN * 2) + (size_t)jbb * 2
                    + (colb ^ ((row & 7) << 4));
        }
    }
    const char* asrc[2];
    {
        const char* abase = (const char*)adj;
#pragma unroll
        for (int p = 0; p < 2; ++p) {
            const int o = p * 4096 + tid * 16;
            const int row = o >> 8;                   // adj row (256B/row)
            const int colb = o & 255;
            asrc[p] = abase + (size_t)(r32 + row) * (NN * 4) + (size_t)jbb * 4
                    + (colb ^ ((row & 7) << 4));
        }
    }

    auto STAGE = [&](int jt, int buf) {
        char* hd = lds_c + buf * 16384 + w * 1024;
        char* ad = lds_c + 32768 + buf * 8192 + w * 1024;
        const size_t hof = (size_t)jt * 128;
        const size_t aof = (size_t)jt * 256;
#pragma unroll
        for (int p = 0; p < 4; ++p) gll16(hsrc[p] + hof, hd + p * 4096);
#pragma unroll
        for (int p = 0; p < 2; ++p) gll16(asrc[p] + aof, ad + p * 4096);
    };

    f32x4 cE[4], nE[4];
    auto loadE2 = [&](int jt, f32x4* E) {
        const int j = jbb + jt * 64 + wj * 32 + quad * 8;
        E[0] = *(const f32x4*)(E2p + j);
        E[1] = *(const f32x4*)(E2p + j + 4);
        E[2] = *(const f32x4*)(E2n + j);
        E[3] = *(const f32x4*)(E2n + j + 4);
    };

    f32x4 acc[8];
#pragma unroll
    for (int t = 0; t < 8; ++t) acc[t] = zero4();
    float zacc = 0.f;

    // prologue
    STAGE(0, 0);
    loadE2(0, cE);
    __syncthreads();

    int cur = 0;
    for (int jt = 0; jt < NSTEP; ++jt) {
        if (jt + 1 < NSTEP) {
            STAGE(jt + 1, cur ^ 1);
            loadE2(jt + 1, nE);
        }
        __builtin_amdgcn_sched_barrier(0);

        // ---- compute on buf cur ----
        const char* hb = lds_c + cur * 16384;
        const char* ab = lds_c + 32768 + cur * 8192;

        const int arow = rh * 16 + fr;
        const unsigned aswz = (unsigned)((arow & 7) << 4);
        const unsigned al = (unsigned)(arow * 256 + wj * 128 + quad * 32);
        int4v g0 = *(const int4v*)(ab + (al ^ aswz));
        int4v g1 = *(const int4v*)(ab + ((al + 16) ^ aswz));

        short8 pa;
        {
            float zs = 0.f;
#pragma unroll
            for (int e = 0; e < 8; ++e) {
                const float cp = (e < 4) ? cE[0][e & 3] : cE[1][e & 3];
                const float cn = (e < 4) ? cE[2][e & 3] : cE[3][e & 3];
                const int gv = (e < 4) ? g0[e & 3] : g1[e & 3];
                const bool hi = cp >= thr;
                const float fc = hi ? cp : cn;
                const float rf = hi ? Rp : Rn;
                float p = fc * rf;
                p = (gv > 0) ? p : 0.f;
                zs += p;
                pa[e] = f2bf(p);
            }
            zacc += zs;
        }

#pragma unroll
        for (int t = 0; t < 8; ++t) {
            const int hrow = t * 16 + fr;
            const short8 bv = *(const short8*)(
                hb + ((unsigned)(hrow * 128 + wj * 64 + quad * 16) ^ ((hrow & 7) << 4)));
            acc[t] = __builtin_amdgcn_mfma_f32_16x16x32_bf16(pa, bv, acc[t], 0, 0, 0);
        }

        __syncthreads();
        cur ^= 1;
        cE[0] = nE[0]; cE[1] = nE[1]; cE[2] = nE[2]; cE[3] = nE[3];
    }

    // ---- reduction (LDS reuse after final barrier) ----
    zacc += __shfl_xor(zacc, 16, 64);
    zacc += __shfl_xor(zacc, 32, 64);
    float* zb = (float*)(lds_c + 49152);
    if (l < 16) zb[w * 16 + l] = zacc;

    float* red = (float*)lds_c;   // 2 regions x 2048 floats (aliases hT buf)
    if (wj == 1) {
#pragma unroll
        for (int t = 0; t < 8; ++t)
            *(f32x4*)(red + rh * 2048 + t * 256 + l * 4) = acc[t];
    }
    __syncthreads();

    if (wj == 0) {
#pragma unroll
        for (int t = 0; t < 8; ++t)
            acc[t] += *(const f32x4*)(red + rh * 2048 + t * 256 + l * 4);
#pragma unroll
        for (int r = 0; r < 4; ++r) {
            const int irow = quad * 4 + r;
            const float z = zb[rh * 32 + irow] + zb[rh * 32 + 16 + irow];
            const int grow = r32 + rh * 16 + irow;
            if (PARTIAL) {
                if (fr == 0) zp[(size_t)jb * NN + grow] = z;
                float* orow = pvp + ((size_t)jb * NN + grow) * 128;
#pragma unroll
                for (int t = 0; t < 8; ++t) orow[t * 16 + fr] = acc[t][r];
            } else {
                const float inv = 1.0f / z;
                float* orow = out + (size_t)grow * 128;
#pragma unroll
                for (int t = 0; t < 8; ++t) {
                    float v = acc[t][r] * inv;
                    orow[t * 16 + fr] = (v > 0.f) ? v : expm1f(v);
                }
            }
        }
    }
}

// ---------- K3: sum partials, divide by Z, ELU ----------
__global__ __launch_bounds__(256) void k3_fin(
        const float* __restrict__ pvp, const float* __restrict__ zp,
        float* __restrict__ out, int jsplit) {
    const int idx = blockIdx.x * 256 + threadIdx.x;
    const int row = idx >> 5;
    const int c = (idx & 31) << 2;
    f32x4 s = zero4();
    float z = 0.f;
    for (int p = 0; p < jsplit; ++p) {
        s += *(const f32x4*)(pvp + ((size_t)p * NN + row) * 128 + c);
        z += zp[(size_t)p * NN + row];
    }
    const float inv = 1.0f / z;
    f32x4 o;
#pragma unroll
    for (int e = 0; e < 4; ++e) {
        float v = s[e] * inv;
        o[e] = (v > 0.f) ? v : expm1f(v);
    }
    *(f32x4*)(out + (size_t)row * 128 + c) = o;
}

extern "C" void kernel_launch(void* const* d_in, const int* in_sizes, int n_in,
                              void* d_out, int out_size, void* d_ws, size_t ws_size,
                              hipStream_t stream) {
    const float* x   = (const float*)d_in[0];   // 8192 x 256
    const float* W   = (const float*)d_in[1];   // 256 x 128
    const float* a   = (const float*)d_in[2];   // 256
    const int*   adj = (const int*)d_in[3];     // 8192 x 8192
    float* out = (float*)d_out;                 // 8192 x 128

    char* ws = (char*)d_ws;
    const size_t MB = 1024 * 1024;
    short* hT  = (short*)ws;                          // 2 MB
    float* E1p = (float*)(ws + 2 * MB);               // 32 KB each
    float* E1n = (float*)(ws + 2 * MB + 32768);
    float* E2p = (float*)(ws + 2 * MB + 65536);
    float* E2n = (float*)(ws + 2 * MB + 98304);
    short* WT  = (short*)(ws + 2 * MB + 131072);      // 64 KB
    const size_t base = 2 * MB + 196608;

    const size_t need2 = base + 2 * ((size_t)NN * 128 * 4) + 2 * ((size_t)NN * 4);
    const bool js2 = (ws_size >= need2);

    float* pvp = (float*)(ws + base);
    float* zp  = (float*)(ws + base + (size_t)2 * NN * 128 * 4);

    k0_wt<<<128, 256, 0, stream>>>(W, WT);
    k1_h<<<256, 128, 0, stream>>>(x, WT, a, hT, E1p, E1n, E2p, E2n);

    if (js2) {
        k2_attn<2, true><<<512, 256, 0, stream>>>(adj, hT, E1p, E1n, E2p, E2n, pvp, zp, nullptr);
        k3_fin<<<1024, 256, 0, stream>>>(pvp, zp, out, 2);
    } else {
        k2_attn<1, false><<<256, 256, 0, stream>>>(adj, hT, E1p, E1n, E2p, E2n, nullptr, nullptr, out);
    }
}

// Round 6
// 94.735 us; speedup vs baseline: 3.9570x; 1.0239x over previous
//
#include <hip/hip_runtime.h>
#include <math.h>

#define NN 8192

typedef __attribute__((ext_vector_type(8))) short short8;
typedef __attribute__((ext_vector_type(4))) short short4v;
typedef __attribute__((ext_vector_type(4))) float f32x4;
typedef __attribute__((ext_vector_type(4))) int int4v;

#define L2E 1.4426950408889634f

typedef __attribute__((address_space(3))) unsigned lds_u32;
typedef __attribute__((address_space(1))) unsigned g_u32;

__device__ __forceinline__ void gll16(const void* g, void* l) {
    __builtin_amdgcn_global_load_lds((const g_u32*)g, (lds_u32*)l, 16, 0, 0);
}

__device__ __forceinline__ short f2bf(float f) {
    union { float f; unsigned u; } v; v.f = f;
    unsigned r = v.u + 0x7fffu + ((v.u >> 16) & 1u);
    return (short)(r >> 16);
}

__device__ __forceinline__ f32x4 zero4() {
    f32x4 v; v[0] = 0.f; v[1] = 0.f; v[2] = 0.f; v[3] = 0.f; return v;
}

// ---------- K0: WT[f][k] = bf16(W[k][f]) ----------
__global__ void k0_wt(const float* __restrict__ W, short* __restrict__ WT) {
    int idx = blockIdx.x * 256 + threadIdx.x;
    if (idx < 256 * 128) {
        int k = idx & 255;
        int f = idx >> 8;
        WT[f * 256 + k] = f2bf(W[k * 128 + f]);
    }
}

// ---------- K1: h = x@W (bf16 MFMA); s1L2E/s2L2E; hT bf16 [128][8192] ----------
__global__ __launch_bounds__(128) void k1_h(
        const float* __restrict__ x, const short* __restrict__ WT,
        const float* __restrict__ a, short* __restrict__ hT,
        float* __restrict__ s1L2E, float* __restrict__ s2L2E) {
    const int w = threadIdx.x >> 6;
    const int l = threadIdx.x & 63;
    const int quad = l >> 4;
    const int fr = l & 15;
    const int i0 = blockIdx.x * 32 + w * 16;

    f32x4 acc[8];
#pragma unroll
    for (int t = 0; t < 8; ++t) acc[t] = zero4();

    const float* xrow = x + (size_t)(i0 + fr) * 256;
#pragma unroll
    for (int kk = 0; kk < 8; ++kk) {
        const int k0 = kk * 32 + quad * 8;
        f32x4 xa = *(const f32x4*)(xrow + k0);
        f32x4 xb = *(const f32x4*)(xrow + k0 + 4);
        short8 av;
#pragma unroll
        for (int e = 0; e < 4; ++e) { av[e] = f2bf(xa[e]); av[4 + e] = f2bf(xb[e]); }
#pragma unroll
        for (int t = 0; t < 8; ++t) {
            short8 bv = *(const short8*)(WT + (t * 16 + fr) * 256 + k0);
            acc[t] = __builtin_amdgcn_mfma_f32_16x16x32_bf16(av, bv, acc[t], 0, 0, 0);
        }
    }

    float s1p[4] = {0.f, 0.f, 0.f, 0.f};
    float s2p[4] = {0.f, 0.f, 0.f, 0.f};
#pragma unroll
    for (int t = 0; t < 8; ++t) {
        float a1v = a[t * 16 + fr];
        float a2v = a[128 + t * 16 + fr];
#pragma unroll
        for (int r = 0; r < 4; ++r) {
            s1p[r] += acc[t][r] * a1v;
            s2p[r] += acc[t][r] * a2v;
        }
    }
#pragma unroll
    for (int r = 0; r < 4; ++r) {
#pragma unroll
        for (int m = 1; m < 16; m <<= 1) {
            s1p[r] += __shfl_xor(s1p[r], m, 64);
            s2p[r] += __shfl_xor(s2p[r], m, 64);
        }
    }
    if (fr == 0) {
#pragma unroll
        for (int r = 0; r < 4; ++r) {
            const int i = i0 + quad * 4 + r;
            s1L2E[i] = s1p[r] * L2E;
            s2L2E[i] = s2p[r] * L2E;
        }
    }

#pragma unroll
    for (int t = 0; t < 8; ++t) {
        short4v hv;
#pragma unroll
        for (int r = 0; r < 4; ++r) hv[r] = f2bf(acc[t][r]);
        *(short4v*)(hT + (size_t)(t * 16 + fr) * NN + i0 + quad * 4) = hv;
    }
}

// ---------- K2: 3-deep counted-vmcnt LDS pipeline, masked-softmax + PV ----------
// Block: 32 rows x JW cols; 4 waves = 2 row-halves x 2 j-halves.
// Per step (64 j): stage hT[128][64] (16KB) + adj[32][64] (8KB) + s2 strip
// (256B, 1KB slot) = 7 gll16/wave into a 3-buffer rotation. Steady state
// keeps 14 gll (2 steps) in flight: s_waitcnt vmcnt(14) + RAW s_barrier
// (never drain to 0 in-loop -- T4). Tail: clamped junk-stages keep the
// vmcnt count uniform; one vmcnt(0) drain after the loop.
// XOR swizzle phys = logical ^ ((row&7)<<4) pre-applied to global sources
// (linear gll dest) + identical XOR on reads (R5-verified, bank-uniform).
template<int JSPLIT, bool PARTIAL>
__global__ __launch_bounds__(256, 2) void k2_attn(
        const int* __restrict__ adj, const short* __restrict__ hT,
        const float* __restrict__ s1g, const float* __restrict__ s2g,
        float* __restrict__ pvp, float* __restrict__ zp,
        float* __restrict__ out) {
    constexpr int JW = NN / JSPLIT;
    constexpr int NSTEP = JW / 64;
    constexpr int BUFB = 25600;           // hT 16K | adj 8K | s2 1K | (pad 0.25K)
    __shared__ __align__(16) char lds_c[3 * BUFB + 256];

    const int tid = threadIdx.x;
    const int w = tid >> 6;
    const int l = tid & 63;
    const int quad = l >> 4;
    const int fr = l & 15;
    const int rh = w >> 1;
    const int wj = w & 1;
    const int rb = blockIdx.x / JSPLIT;
    const int jb = blockIdx.x % JSPLIT;
    const int r32 = rb * 32;
    const int jbb = jb * JW;

    const float S = s1g[r32 + rh * 16 + fr];   // s1*log2e for this lane's row

    // ---- pre-swizzled per-lane global sources ----
    const char* hsrc[4];
    {
        const char* hbase = (const char*)hT;
#pragma unroll
        for (int p = 0; p < 4; ++p) {
            const int o = p * 4096 + tid * 16;        // LDS-linear offset
            const int row = o >> 7;                   // feature row (128B/row)
            const int colb = o & 127;
            hsrc[p] = hbase + (size_t)row * (NN * 2) + (size_t)jbb * 2
                    + (colb ^ ((row & 7) << 4));
        }
    }
    const char* asrc[2];
    {
        const char* abase = (const char*)adj;
#pragma unroll
        for (int p = 0; p < 2; ++p) {
            const int o = p * 4096 + tid * 16;
            const int row = o >> 8;                   // adj row (256B/row)
            const int colb = o & 255;
            asrc[p] = abase + (size_t)(r32 + row) * (NN * 4) + (size_t)jbb * 4
                    + (colb ^ ((row & 7) << 4));
        }
    }
    // s2 strip source: lanes 0-15 carry the 256B tile, rest clamped (junk)
    const char* csrc = (const char*)s2g + (size_t)jbb * 4 + (l < 16 ? l * 16 : 240);

    auto STAGE = [&](int jt, int buf) {
        jt = (jt < NSTEP) ? jt : NSTEP - 1;           // tail clamp (junk stage)
        char* hd = lds_c + buf * BUFB + w * 1024;
        char* ad = lds_c + buf * BUFB + 16384 + w * 1024;
        char* cd = lds_c + buf * BUFB + 24576;
        const size_t hof = (size_t)jt * 128;
        const size_t aof = (size_t)jt * 256;
#pragma unroll
        for (int p = 0; p < 4; ++p) gll16(hsrc[p] + hof, hd + p * 4096);
#pragma unroll
        for (int p = 0; p < 2; ++p) gll16(asrc[p] + aof, ad + p * 4096);
        gll16(csrc + aof, cd);                        // all waves, same data (benign WAW)
    };

    f32x4 acc[8];
#pragma unroll
    for (int t = 0; t < 8; ++t) acc[t] = zero4();
    float zacc = 0.f;

    // prologue: 3 tiles in flight (21 gll/wave)
    STAGE(0, 0); STAGE(1, 1); STAGE(2, 2);

    int cur = 0;
    for (int t = 0; t < NSTEP; ++t) {
        // buf `cur` ready once only 2 newer stages (14 gll) remain outstanding
        asm volatile("s_waitcnt vmcnt(14)" ::: "memory");
        __builtin_amdgcn_s_barrier();
        __builtin_amdgcn_sched_barrier(0);

        const char* hb = lds_c + cur * BUFB;
        const char* ab = lds_c + cur * BUFB + 16384;
        const float* cb = (const float*)(lds_c + cur * BUFB + 24576);

        const int arow = rh * 16 + fr;
        const unsigned aswz = (unsigned)((arow & 7) << 4);
        const unsigned al = (unsigned)(arow * 256 + wj * 128 + quad * 32);
        const int4v g0 = *(const int4v*)(ab + (al ^ aswz));
        const int4v g1 = *(const int4v*)(ab + ((al + 16) ^ aswz));
        const f32x4 c0 = *(const f32x4*)(cb + wj * 32 + quad * 8);
        const f32x4 c1 = *(const f32x4*)(cb + wj * 32 + quad * 8 + 4);

        short8 pa;
        {
            float zs = 0.f;
#pragma unroll
            for (int e = 0; e < 8; ++e) {
                const float cv = (e < 4) ? c0[e & 3] : c1[e & 3];
                const int gv = (e < 4) ? g0[e & 3] : g1[e & 3];
                const float u = S + cv;                 // (s1+s2)*log2e
                const float tt = fmaxf(u, 0.2f * u);    // leaky-relu in log2 space
                const float p = (gv > 0) ? exp2f(tt) : 0.f;
                zs += p;
                pa[e] = f2bf(p);
            }
            zacc += zs;
        }

#pragma unroll
        for (int t8 = 0; t8 < 8; ++t8) {
            const int hrow = t8 * 16 + fr;
            const short8 bv = *(const short8*)(
                hb + ((unsigned)(hrow * 128 + wj * 64 + quad * 16) ^ ((hrow & 7) << 4)));
            acc[t8] = __builtin_amdgcn_mfma_f32_16x16x32_bf16(pa, bv, acc[t8], 0, 0, 0);
        }

        __builtin_amdgcn_sched_barrier(0);
        asm volatile("" ::: "memory");
        __builtin_amdgcn_s_barrier();                 // all waves done reading buf cur

        STAGE(t + 3, cur);                            // refill the buffer just freed
        cur = (cur == 2) ? 0 : cur + 1;
    }

    asm volatile("s_waitcnt vmcnt(0)" ::: "memory");  // drain junk stages before aliasing
    __syncthreads();

    // ---- reduction (red aliases buffer 0's hT region) ----
    zacc += __shfl_xor(zacc, 16, 64);
    zacc += __shfl_xor(zacc, 32, 64);
    float* zb = (float*)(lds_c + 3 * BUFB);
    if (l < 16) zb[w * 16 + l] = zacc;

    float* red = (float*)lds_c;   // 2 regions x 2048 floats
    if (wj == 1) {
#pragma unroll
        for (int t = 0; t < 8; ++t)
            *(f32x4*)(red + rh * 2048 + t * 256 + l * 4) = acc[t];
    }
    __syncthreads();

    if (wj == 0) {
#pragma unroll
        for (int t = 0; t < 8; ++t)
            acc[t] += *(const f32x4*)(red + rh * 2048 + t * 256 + l * 4);
#pragma unroll
        for (int r = 0; r < 4; ++r) {
            const int irow = quad * 4 + r;
            const float z = zb[rh * 32 + irow] + zb[rh * 32 + 16 + irow];
            const int grow = r32 + rh * 16 + irow;
            if (PARTIAL) {
                if (fr == 0) zp[(size_t)jb * NN + grow] = z;
                float* orow = pvp + ((size_t)jb * NN + grow) * 128;
#pragma unroll
                for (int t = 0; t < 8; ++t) orow[t * 16 + fr] = acc[t][r];
            } else {
                const float inv = 1.0f / z;
                float* orow = out + (size_t)grow * 128;
#pragma unroll
                for (int t = 0; t < 8; ++t) {
                    float v = acc[t][r] * inv;
                    orow[t * 16 + fr] = (v > 0.f) ? v : expm1f(v);
                }
            }
        }
    }
}

// ---------- K3: sum partials, divide by Z, ELU ----------
__global__ __launch_bounds__(256) void k3_fin(
        const float* __restrict__ pvp, const float* __restrict__ zp,
        float* __restrict__ out, int jsplit) {
    const int idx = blockIdx.x * 256 + threadIdx.x;
    const int row = idx >> 5;
    const int c = (idx & 31) << 2;
    f32x4 s = zero4();
    float z = 0.f;
    for (int p = 0; p < jsplit; ++p) {
        s += *(const f32x4*)(pvp + ((size_t)p * NN + row) * 128 + c);
        z += zp[(size_t)p * NN + row];
    }
    const float inv = 1.0f / z;
    f32x4 o;
#pragma unroll
    for (int e = 0; e < 4; ++e) {
        float v = s[e] * inv;
        o[e] = (v > 0.f) ? v : expm1f(v);
    }
    *(f32x4*)(out + (size_t)row * 128 + c) = o;
}

extern "C" void kernel_launch(void* const* d_in, const int* in_sizes, int n_in,
                              void* d_out, int out_size, void* d_ws, size_t ws_size,
                              hipStream_t stream) {
    const float* x   = (const float*)d_in[0];   // 8192 x 256
    const float* W   = (const float*)d_in[1];   // 256 x 128
    const float* a   = (const float*)d_in[2];   // 256
    const int*   adj = (const int*)d_in[3];     // 8192 x 8192
    float* out = (float*)d_out;                 // 8192 x 128

    char* ws = (char*)d_ws;
    const size_t MB = 1024 * 1024;
    short* hT    = (short*)ws;                        // 2 MB
    float* s1L2E = (float*)(ws + 2 * MB);             // 32 KB
    float* s2L2E = (float*)(ws + 2 * MB + 32768);     // 32 KB
    short* WT    = (short*)(ws + 2 * MB + 65536);     // 64 KB
    const size_t base = 2 * MB + 131072;

    const size_t need2 = base + 2 * ((size_t)NN * 128 * 4) + 2 * ((size_t)NN * 4);
    const bool js2 = (ws_size >= need2);

    float* pvp = (float*)(ws + base);
    float* zp  = (float*)(ws + base + (size_t)2 * NN * 128 * 4);

    k0_wt<<<128, 256, 0, stream>>>(W, WT);
    k1_h<<<256, 128, 0, stream>>>(x, WT, a, hT, s1L2E, s2L2E);

    if (js2) {
        k2_attn<2, true><<<512, 256, 0, stream>>>(adj, hT, s1L2E, s2L2E, pvp, zp, nullptr);
        k3_fin<<<1024, 256, 0, stream>>>(pvp, zp, out, 2);
    } else {
        k2_attn<1, false><<<256, 256, 0, stream>>>(adj, hT, s1L2E, s2L2E, nullptr, nullptr, out);
    }
}